// Round 2
// baseline (400.236 us; speedup 1.0000x reference)
//
#include <hip/hip_runtime.h>
#include <hip/hip_bf16.h>

#define HH   300
#define NB   128
#define NTT  64
#define NP   8192        // B*T
#define NCH  12
#define NROWS (NP*NCH)   // 98304
#define KPAD 320         // padded K (300 -> 320)
#define EPAD 208         // padded N (200 -> 208)
#define NTI  13          // 208/16 n-tiles

typedef __attribute__((ext_vector_type(8))) short short8;
typedef __attribute__((ext_vector_type(4))) float f32x4;

__device__ __forceinline__ float fsig(float x){
  return __builtin_amdgcn_rcpf(1.f + __expf(-x));
}
__device__ __forceinline__ float ftanh(float x){
  float e = __expf(2.f*x);
  return 1.f - 2.f*__builtin_amdgcn_rcpf(e + 1.f);   // safe at +/-inf
}

// ---------------- K0: Att1[300:600,0:200] -> bf16 transposed padded [208][320]
__global__ __launch_bounds__(256) void k_prep(const float* __restrict__ Att1,
                                              __hip_bfloat16* __restrict__ a1t)
{
  int id = blockIdx.x*256 + threadIdx.x;
  if (id >= EPAD*KPAD) return;
  int e = id / KPAD, k = id - e*KPAD;
  float v = (e < 200 && k < HH) ? Att1[(size_t)(HH+k)*200 + e] : 0.f;
  a1t[id] = __float2bfloat16(v);
}

// ---------------- K1: htarget[p][j] (f32), LSTM zero-state of tgt GEMM (K=5)
__global__ __launch_bounds__(256) void k_htarget(
    const float* __restrict__ extras, const float* __restrict__ Wt,
    const float* __restrict__ bti, const float* __restrict__ bth,
    float* __restrict__ ht)
{
  int id = blockIdx.x*256 + threadIdx.x;
  if (id >= NP*HH) return;
  int p = id / HH, j = id - p*HH;
  const float* tg = extras + (size_t)p*17;
  float tv[5];
  #pragma unroll
  for (int f=0; f<5; f++) tv[f] = tg[f];
  float gi = bti[j]     + bth[j];
  float gg = bti[j+600] + bth[j+600];
  float go = bti[j+900] + bth[j+900];
  const float* w0 = Wt + (size_t)j*5;
  const float* w1 = Wt + (size_t)(j+600)*5;
  const float* w2 = Wt + (size_t)(j+900)*5;
  #pragma unroll
  for (int f=0; f<5; f++){ gi += tv[f]*w0[f]; gg += tv[f]*w1[f]; go += tv[f]*w2[f]; }
  float cc = fsig(gi)*ftanh(gg);
  ht[id] = fsig(go)*ftanh(cc);
}

// ---------------- K2: h[p][c][j] (bf16, rows padded to 320) — gates i,g,o only
#define K2P 64
__global__ __launch_bounds__(320) void k_hgen(
    const float* __restrict__ li, const float* __restrict__ Wih,
    const float* __restrict__ bih, const float* __restrict__ bhh,
    __hip_bfloat16* __restrict__ hpad)
{
  int c  = blockIdx.x % NCH;
  int p0 = (blockIdx.x / NCH) * K2P;
  __shared__ float s_s[K2P][8];
  int tid = threadIdx.x;
  for (int i = tid; i < K2P*8; i += 320){
    int ps = i >> 3, f = i & 7;
    s_s[ps][f] = li[(size_t)(p0+ps)*240 + f*12 + c];
  }
  __syncthreads();
  int j = tid;
  if (j < HH){
    const float* wb = Wih + (size_t)c*9600;
    float wi[8], wg[8], wo[8];
    #pragma unroll
    for (int f=0; f<8; f++){
      wi[f] = wb[(size_t)j*8+f];
      wg[f] = wb[(size_t)(j+600)*8+f];
      wo[f] = wb[(size_t)(j+900)*8+f];
    }
    float bi = bih[c*1200+j]     + bhh[c*1200+j];
    float bg = bih[c*1200+j+600] + bhh[c*1200+j+600];
    float bo = bih[c*1200+j+900] + bhh[c*1200+j+900];
    for (int ps=0; ps<K2P; ps++){
      float gi=bi, gg=bg, go=bo;
      #pragma unroll
      for (int f=0; f<8; f++){
        float s = s_s[ps][f];
        gi += s*wi[f]; gg += s*wg[f]; go += s*wo[f];
      }
      float cc = fsig(gi)*ftanh(gg);
      float hv = fsig(go)*ftanh(cc);
      hpad[(size_t)((p0+ps)*NCH + c)*KPAD + j] = __float2bfloat16(hv);
    }
  } else if (j < KPAD){
    __hip_bfloat16 z = __float2bfloat16(0.f);
    for (int ps=0; ps<K2P; ps++)
      hpad[(size_t)((p0+ps)*NCH + c)*KPAD + j] = z;
  }
}

// ---------------- K3: ta[p][e] = htarget[p,:] . Att1[0:300, e]  (f32 vector)
#define K3P 32
__global__ __launch_bounds__(256) void k_ta(
    const float* __restrict__ ht, const float* __restrict__ Att1,
    float* __restrict__ ta)
{
  int p0 = blockIdx.x * K3P;
  __shared__ float s_h[K3P][HH];
  for (int i = threadIdx.x; i < K3P*HH; i += 256)
    ((float*)s_h)[i] = ht[(size_t)p0*HH + i];
  __syncthreads();
  int e = threadIdx.x;
  if (e >= 200) return;
  float acc[K3P];
  #pragma unroll
  for (int ps=0; ps<K3P; ps++) acc[ps] = 0.f;
  for (int d=0; d<HH; d+=4){
    float a0 = Att1[(size_t)(d+0)*200+e];
    float a1 = Att1[(size_t)(d+1)*200+e];
    float a2 = Att1[(size_t)(d+2)*200+e];
    float a3 = Att1[(size_t)(d+3)*200+e];
    #pragma unroll
    for (int ps=0; ps<K3P; ps++){
      float4 s4 = *(const float4*)&s_h[ps][d];
      acc[ps] += s4.x*a0 + s4.y*a1 + s4.z*a2 + s4.w*a3;
    }
  }
  #pragma unroll
  for (int ps=0; ps<K3P; ps++)
    ta[(size_t)(p0+ps)*200 + e] = acc[ps];
}

// ---------------- K4: MFMA GEMM [rows=98304, K=320]x[320, 208] + fused score
__global__ __launch_bounds__(256) void k_score(
    const short* __restrict__ hpad, const short* __restrict__ a1t,
    const float* __restrict__ ta, const float* __restrict__ ba1,
    const float* __restrict__ att2, const float* __restrict__ ba2,
    const float* __restrict__ li, float* __restrict__ score)
{
  int wave = threadIdx.x >> 6;
  int lane = threadIdx.x & 63;
  int lr = lane & 15;     // A row / B col / C col
  int lg = lane >> 4;     // k-group
  int m0 = blockIdx.x * 128 + wave * 32;
  f32x4 acc[2][NTI];
  #pragma unroll
  for (int mt=0; mt<2; mt++)
    #pragma unroll
    for (int nt=0; nt<NTI; nt++)
      acc[mt][nt] = (f32x4){0.f,0.f,0.f,0.f};
  const short* ap = hpad + (size_t)(m0 + lr)*KPAD + lg*8;
  const short* bp = a1t  + (size_t)lr*KPAD + lg*8;
  for (int k0=0; k0<KPAD; k0+=32){
    short8 a0 = *(const short8*)(ap + k0);
    short8 a1 = *(const short8*)(ap + 16*KPAD + k0);
    #pragma unroll
    for (int nt=0; nt<NTI; nt++){
      short8 b = *(const short8*)(bp + (size_t)nt*16*KPAD + k0);
      acc[0][nt] = __builtin_amdgcn_mfma_f32_16x16x32_bf16(a0, b, acc[0][nt], 0, 0, 0);
      acc[1][nt] = __builtin_amdgcn_mfma_f32_16x16x32_bf16(a1, b, acc[1][nt], 0, 0, 0);
    }
  }
  float w200 = att2[200], w201 = att2[201], b2 = ba2[0];
  #pragma unroll
  for (int mt=0; mt<2; mt++){
    int rbase = m0 + mt*16 + lg*4;
    float sacc[4] = {0.f,0.f,0.f,0.f};
    #pragma unroll
    for (int nt=0; nt<NTI; nt++){
      int e = nt*16 + lr;
      if (e < 200){
        float b1  = ba1[e];
        float a2v = att2[e];
        #pragma unroll
        for (int i=0; i<4; i++){
          int r = rbase + i;
          int p = r / NCH;
          float v = acc[mt][nt][i] + ta[(size_t)p*200 + e] + b1;
          sacc[i] += fmaxf(v, 0.f) * a2v;
        }
      }
    }
    #pragma unroll
    for (int i=0; i<4; i++){
      float s = sacc[i];
      s += __shfl_xor(s, 1);
      s += __shfl_xor(s, 2);
      s += __shfl_xor(s, 4);
      s += __shfl_xor(s, 8);
      if (lr == 0){
        int r = rbase + i;
        int p = r / NCH;
        int ch = r - p*NCH;
        float w0 = li[(size_t)p*240 + 84 + ch];  // local_inputs[p,7,ch]
        float w1 = li[(size_t)p*240 + 72 + ch];  // local_inputs[p,6,ch]
        score[r] = fmaxf(s + w0*w200 + w1*w201 + b2, 0.f);
      }
    }
  }
}

// ---------------- K5: softmax over channels -> w_soft[t][c][b]
__global__ void k_softmax(const float* __restrict__ score, float* __restrict__ wsoft)
{
  int t = blockIdx.x;
  int b = threadIdx.x;
  const float* s = score + ((size_t)b*NTT + t)*NCH;
  float v[NCH];
  float m = -1e30f;
  #pragma unroll
  for (int c=0; c<NCH; c++){ v[c] = s[c]; m = fmaxf(m, v[c]); }
  float sum = 0.f;
  #pragma unroll
  for (int c=0; c<NCH; c++){ v[c] = __expf(v[c]-m); sum += v[c]; }
  float inv = __builtin_amdgcn_rcpf(sum);
  #pragma unroll
  for (int c=0; c<NCH; c++)
    wsoft[((size_t)t*NCH + c)*NB + b] = v[c]*inv;
}

// ---------------- K6: fusion (w scramble) + fuse2 + Wout + labels passthrough
#define K6P 16
__global__ __launch_bounds__(256) void k_out(
    const __hip_bfloat16* __restrict__ hpad, const float* __restrict__ ht,
    const float* __restrict__ wsoft, const float* __restrict__ fuse2,
    const float* __restrict__ bf2, const float* __restrict__ Wout,
    const float* __restrict__ bout, const float* __restrict__ labels,
    float* __restrict__ out)
{
  int p0 = blockIdx.x * K6P;
  __shared__ float s_fus[K6P][600];
  __shared__ float s_w[K6P][NCH];
  __shared__ float s_fz[K6P][200];
  int tid = threadIdx.x;
  for (int i = tid; i < K6P*NCH; i += 256){
    int ps = i / NCH, c = i - ps*NCH;
    int p = p0 + ps;
    int b = p >> 6, t = p & 63;
    int idx = b*NCH + c;           // reference's reshape scramble
    s_w[ps][c] = wsoft[((size_t)t*NCH + (idx>>7))*NB + (idx & 127)];
  }
  __syncthreads();
  for (int i = tid; i < K6P*600; i += 256){
    int ps = i / 600, d = i - ps*600;
    int p = p0 + ps;
    float v;
    if (d < HH){
      float a = 0.f;
      #pragma unroll
      for (int c=0; c<NCH; c++)
        a += __bfloat162float(hpad[(size_t)(p*NCH+c)*KPAD + d]) * s_w[ps][c];
      v = a;
    } else {
      v = ht[(size_t)p*HH + (d-HH)];
    }
    s_fus[ps][d] = v;
  }
  __syncthreads();
  int e = tid;
  if (e < 200){
    float acc[K6P];
    #pragma unroll
    for (int ps=0; ps<K6P; ps++) acc[ps] = bf2[e];
    for (int d=0; d<600; d+=4){
      float f0 = fuse2[(size_t)(d+0)*200+e];
      float f1 = fuse2[(size_t)(d+1)*200+e];
      float f2v= fuse2[(size_t)(d+2)*200+e];
      float f3 = fuse2[(size_t)(d+3)*200+e];
      #pragma unroll
      for (int ps=0; ps<K6P; ps++){
        float4 s4 = *(const float4*)&s_fus[ps][d];
        acc[ps] += s4.x*f0 + s4.y*f1 + s4.z*f2v + s4.w*f3;
      }
    }
    #pragma unroll
    for (int ps=0; ps<K6P; ps++) s_fz[ps][e] = acc[ps];
  }
  __syncthreads();
  int ps = tid >> 4, l16 = tid & 15;
  float part = 0.f;
  for (int ee = l16; ee < 200; ee += 16)
    part += s_fz[ps][ee] * Wout[ee];
  part += __shfl_xor(part, 1);
  part += __shfl_xor(part, 2);
  part += __shfl_xor(part, 4);
  part += __shfl_xor(part, 8);
  if (l16 == 0){
    int p = p0 + ps;
    int b = p >> 6, t = p & 63;
    out[t*NB + b] = part + bout[0];
    out[NP + t*NB + b] = labels[p];
  }
}

extern "C" void kernel_launch(void* const* d_in, const int* in_sizes, int n_in,
                              void* d_out, int out_size, void* d_ws, size_t ws_size,
                              hipStream_t stream)
{
  const float* li     = (const float*)d_in[0];
  const float* labels = (const float*)d_in[1];
  const float* extras = (const float*)d_in[2];
  const float* Wih    = (const float*)d_in[5];
  const float* bih    = (const float*)d_in[6];
  const float* bhh    = (const float*)d_in[7];
  const float* Wt     = (const float*)d_in[8];
  const float* bti    = (const float*)d_in[9];
  const float* bth    = (const float*)d_in[10];
  const float* Att1   = (const float*)d_in[11];
  const float* ba1    = (const float*)d_in[12];
  const float* Att2   = (const float*)d_in[13];
  const float* ba2    = (const float*)d_in[14];
  const float* fuse2  = (const float*)d_in[15];
  const float* bf2    = (const float*)d_in[16];
  const float* Wout   = (const float*)d_in[17];
  const float* bout   = (const float*)d_in[18];
  float* out = (float*)d_out;

  char* ws = (char*)d_ws;
  __hip_bfloat16* hpad = (__hip_bfloat16*)ws;                       // 62,914,560 B
  float* ht    = (float*)(ws + 62914560);                           //  9,830,400 B
  float* ta    = (float*)(ws + 72744960);                           //  6,553,600 B
  float* score = (float*)(ws + 79298560);                           //    393,216 B
  float* wsoft = (float*)(ws + 79691776);                           //    393,216 B
  __hip_bfloat16* a1t = (__hip_bfloat16*)(ws + 80084992);           //    133,120 B

  k_prep<<<(EPAD*KPAD+255)/256, 256, 0, stream>>>(Att1, a1t);
  k_htarget<<<(NP*HH+255)/256, 256, 0, stream>>>(extras, Wt, bti, bth, ht);
  k_hgen<<<NCH*(NP/K2P), 320, 0, stream>>>(li, Wih, bih, bhh, hpad);
  k_ta<<<NP/K3P, 256, 0, stream>>>(ht, Att1, ta);
  k_score<<<NROWS/128, 256, 0, stream>>>((const short*)hpad, (const short*)a1t,
                                         ta, ba1, Att2, ba2, li, score);
  k_softmax<<<NTT, NB, 0, stream>>>(score, wsoft);
  k_out<<<NP/K6P, 256, 0, stream>>>(hpad, ht, wsoft, fuse2, bf2, Wout, bout,
                                    labels, out);
}

// Round 3
// 328.576 us; speedup vs baseline: 1.2181x; 1.2181x over previous
//
#include <hip/hip_runtime.h>
#include <hip/hip_bf16.h>

#define HH   300
#define NB   128
#define NTT  64
#define NP   8192        // B*T
#define NCH  12
#define KPAD 320         // padded K (300 -> 320)
#define NTI  13          // 208/16 n-tiles
#define K6K  640         // k_out padded K (600 -> 640)

typedef __attribute__((ext_vector_type(8))) short short8;
typedef __attribute__((ext_vector_type(4))) short short4v;
typedef __attribute__((ext_vector_type(4))) float f32x4;

__device__ __forceinline__ float fsig(float x){
  return __builtin_amdgcn_rcpf(1.f + __expf(-x));
}
__device__ __forceinline__ float ftanh(float x){
  float e = __expf(2.f*x);
  return 1.f - 2.f*__builtin_amdgcn_rcpf(e + 1.f);   // safe at +/-inf
}
__device__ __forceinline__ float bf2f(unsigned short u){
  return __uint_as_float(((unsigned)u) << 16);
}
__device__ __forceinline__ unsigned short f2bf(float f){
  __hip_bfloat16 h = __float2bfloat16(f);
  return *reinterpret_cast<unsigned short*>(&h);
}
// XOR-swizzled LDS short-index; strideShorts*2 must be a multiple of 128B
__device__ __forceinline__ int swzi(int row, int col, int strideShorts){
  int byte = row*(strideShorts*2) + (col<<1);
  byte ^= (row & 7) << 4;
  return byte >> 1;
}

// ---------- K0: weight tables (bf16, transposed, padded) + epilogue constant
// a1hi[208][320] = Att1[300+k][e];  a1lo[208][320] = Att1[k][e];
// f2t[208][640]  = fuse2[d][e];     kconst = sum_e bf2[e]*Wout[e] + bout
__global__ __launch_bounds__(256) void k_prep(
    const float* __restrict__ Att1, const float* __restrict__ fuse2,
    const float* __restrict__ bf2, const float* __restrict__ Wout,
    const float* __restrict__ bout,
    unsigned short* __restrict__ a1hi, unsigned short* __restrict__ a1lo,
    unsigned short* __restrict__ f2t, float* __restrict__ kconst)
{
  int bid = blockIdx.x, tid = threadIdx.x;
  if (bid == 1040){
    __shared__ float red[256];
    red[tid] = (tid < 200) ? bf2[tid]*Wout[tid] : 0.f;
    __syncthreads();
    for (int s=128; s>0; s>>=1){
      if (tid < s) red[tid] += red[tid+s];
      __syncthreads();
    }
    if (tid == 0) kconst[0] = red[0] + bout[0];
    return;
  }
  int id = bid*256 + tid;
  if (id < 66560){
    int e = id/320, k = id - e*320;
    float v = (e<200 && k<300) ? Att1[(size_t)(300+k)*200 + e] : 0.f;
    a1hi[id] = f2bf(v);
  } else if (id < 133120){
    int j = id - 66560, e = j/320, k = j - e*320;
    float v = (e<200 && k<300) ? Att1[(size_t)k*200 + e] : 0.f;
    a1lo[j] = f2bf(v);
  } else {
    int j = id - 133120, e = j/K6K, d = j - e*K6K;
    float v = (e<200 && d<600) ? fuse2[(size_t)d*200 + e] : 0.f;
    f2t[j] = f2bf(v);
  }
}

// ---------- K1: htarget bf16 [8192][320] (zero-padded cols 300..319)
__global__ __launch_bounds__(256) void k_htarget(
    const float* __restrict__ extras, const float* __restrict__ Wt,
    const float* __restrict__ bti, const float* __restrict__ bth,
    unsigned short* __restrict__ htpad)
{
  int id = blockIdx.x*256 + threadIdx.x;   // NP*320
  int p = id / 320, j = id - p*320;
  if (j >= 300){ htpad[id] = 0; return; }
  const float* tg = extras + (size_t)p*17;
  float tv[5];
  #pragma unroll
  for (int f=0; f<5; f++) tv[f] = tg[f];
  float gi = bti[j]     + bth[j];
  float gg = bti[j+600] + bth[j+600];
  float go = bti[j+900] + bth[j+900];
  const float* w0 = Wt + (size_t)j*5;
  const float* w1 = Wt + (size_t)(j+600)*5;
  const float* w2 = Wt + (size_t)(j+900)*5;
  #pragma unroll
  for (int f=0; f<5; f++){ gi += tv[f]*w0[f]; gg += tv[f]*w1[f]; go += tv[f]*w2[f]; }
  float cc = fsig(gi)*ftanh(gg);
  htpad[id] = f2bf(fsig(go)*ftanh(cc));
}

// ---------- K2: ta[8192][200] = htarget . Att1[0:300,:]  via MFMA
__global__ __launch_bounds__(256) void k_ta(
    const unsigned short* __restrict__ htpad,
    const unsigned short* __restrict__ a1lo, float* __restrict__ ta)
{
  int wave = threadIdx.x >> 6, lane = threadIdx.x & 63;
  int lr = lane & 15, lg = lane >> 4;
  int r0 = blockIdx.x*64 + wave*16;
  f32x4 acc[NTI];
  #pragma unroll
  for (int nt=0; nt<NTI; nt++) acc[nt] = (f32x4){0.f,0.f,0.f,0.f};
  const unsigned short* ap = htpad + (size_t)(r0+lr)*KPAD + lg*8;
  const unsigned short* bp = a1lo + (size_t)lr*KPAD + lg*8;
  for (int k0=0; k0<KPAD; k0+=32){
    short8 a = *(const short8*)(ap + k0);
    #pragma unroll
    for (int nt=0; nt<NTI; nt++){
      short8 b = *(const short8*)(bp + (size_t)nt*16*KPAD + k0);
      acc[nt] = __builtin_amdgcn_mfma_f32_16x16x32_bf16(a, b, acc[nt], 0, 0, 0);
    }
  }
  #pragma unroll
  for (int nt=0; nt<NTI; nt++){
    int e = nt*16 + lr;
    if (e < 200){
      #pragma unroll
      for (int i=0; i<4; i++)
        ta[(size_t)(r0 + lg*4 + i)*200 + e] = acc[nt][i];
    }
  }
}

// ---------- K3: fused h-gen (into LDS + global, c-major) + score MFMA + epilogue
// block: c = bid/128 fixed, 64 consecutive p.  h stored hpad2[(c*8192+p)*320+j]
__global__ __launch_bounds__(256) void k_hs(
    const float* __restrict__ li, const float* __restrict__ Wih,
    const float* __restrict__ bih, const float* __restrict__ bhh,
    const unsigned short* __restrict__ a1hi, const float* __restrict__ ta,
    const float* __restrict__ ba1, const float* __restrict__ att2,
    const float* __restrict__ ba2, unsigned short* __restrict__ hpad2,
    float* __restrict__ score)
{
  int c  = blockIdx.x >> 7;
  int p0 = (blockIdx.x & 127) << 6;
  int tid = threadIdx.x;
  __shared__ float s_s[64][8];
  __shared__ unsigned short s_h[64*KPAD];   // swizzled, stride 640B (128B-mult)

  for (int i = tid; i < 64*8; i += 256){
    int ps = i >> 3, f = i & 7;
    s_s[ps][f] = li[(size_t)(p0+ps)*240 + f*12 + c];
  }
  __syncthreads();

  // phase 1: generate h rows (gates i,g,o; f unused by zero-state LSTM)
  for (int j = tid; j < KPAD; j += 256){
    if (j < 300){
      const float* wb = Wih + (size_t)c*9600;
      float wi[8], wg[8], wo[8];
      #pragma unroll
      for (int f=0; f<8; f++){
        wi[f] = wb[(size_t)j*8+f];
        wg[f] = wb[(size_t)(j+600)*8+f];
        wo[f] = wb[(size_t)(j+900)*8+f];
      }
      float bi = bih[c*1200+j]     + bhh[c*1200+j];
      float bg = bih[c*1200+j+600] + bhh[c*1200+j+600];
      float bo = bih[c*1200+j+900] + bhh[c*1200+j+900];
      for (int ps=0; ps<64; ps++){
        float gi=bi, gg=bg, go=bo;
        #pragma unroll
        for (int f=0; f<8; f++){
          float s = s_s[ps][f];
          gi += s*wi[f]; gg += s*wg[f]; go += s*wo[f];
        }
        float cc = fsig(gi)*ftanh(gg);
        unsigned short hv = f2bf(fsig(go)*ftanh(cc));
        s_h[swzi(ps, j, KPAD)] = hv;
        hpad2[(size_t)(c*8192 + p0 + ps)*KPAD + j] = hv;
      }
    } else {
      for (int ps=0; ps<64; ps++){
        s_h[swzi(ps, j, KPAD)] = 0;
        hpad2[(size_t)(c*8192 + p0 + ps)*KPAD + j] = 0;
      }
    }
  }
  __syncthreads();

  // phase 2: per wave one 16-row m-tile x 13 n-tiles, K=320
  int wave = tid >> 6, lane = tid & 63;
  int lr = lane & 15, lg = lane >> 4;
  f32x4 acc[NTI];
  #pragma unroll
  for (int nt=0; nt<NTI; nt++) acc[nt] = (f32x4){0.f,0.f,0.f,0.f};
  const unsigned short* bp = a1hi + (size_t)lr*KPAD + lg*8;
  int arow = wave*16 + lr;
  for (int k0=0; k0<KPAD; k0+=32){
    short8 a = *(const short8*)&s_h[swzi(arow, lg*8 + k0, KPAD)];
    #pragma unroll
    for (int nt=0; nt<NTI; nt++){
      short8 b = *(const short8*)(bp + (size_t)nt*16*KPAD + k0);
      acc[nt] = __builtin_amdgcn_mfma_f32_16x16x32_bf16(a, b, acc[nt], 0, 0, 0);
    }
  }

  // epilogue: relu(acc + ta + ba1) . att2  -> score[p*12+c]
  float w200 = att2[200], w201 = att2[201], b2 = ba2[0];
  float sacc[4] = {0.f,0.f,0.f,0.f};
  #pragma unroll
  for (int nt=0; nt<NTI; nt++){
    int e = nt*16 + lr;
    if (e < 200){
      float b1  = ba1[e];
      float a2v = att2[e];
      #pragma unroll
      for (int i=0; i<4; i++){
        int p = p0 + wave*16 + lg*4 + i;
        float v = acc[nt][i] + ta[(size_t)p*200 + e] + b1;
        sacc[i] += fmaxf(v, 0.f) * a2v;
      }
    }
  }
  #pragma unroll
  for (int i=0; i<4; i++){
    float s = sacc[i];
    s += __shfl_xor(s, 1);
    s += __shfl_xor(s, 2);
    s += __shfl_xor(s, 4);
    s += __shfl_xor(s, 8);
    if (lr == 0){
      int p = p0 + wave*16 + lg*4 + i;
      float w0 = li[(size_t)p*240 + 84 + c];   // local_inputs[p,7,c]
      float w1 = li[(size_t)p*240 + 72 + c];   // local_inputs[p,6,c]
      score[(size_t)p*NCH + c] = fmaxf(s + w0*w200 + w1*w201 + b2, 0.f);
    }
  }
}

// ---------- K4: softmax over channels -> wsoft[t][c][b]
__global__ void k_softmax(const float* __restrict__ score, float* __restrict__ wsoft)
{
  int t = blockIdx.x;
  int b = threadIdx.x;
  const float* s = score + ((size_t)b*NTT + t)*NCH;
  float v[NCH];
  float m = -1e30f;
  #pragma unroll
  for (int c=0; c<NCH; c++){ v[c] = s[c]; m = fmaxf(m, v[c]); }
  float sum = 0.f;
  #pragma unroll
  for (int c=0; c<NCH; c++){ v[c] = __expf(v[c]-m); sum += v[c]; }
  float inv = __builtin_amdgcn_rcpf(sum);
  #pragma unroll
  for (int c=0; c<NCH; c++)
    wsoft[((size_t)t*NCH + c)*NB + b] = v[c]*inv;
}

// ---------- K5: fusion build (bf16 LDS) + MFMA vs fuse2^T + Wout dot
#define K6P 16
__global__ __launch_bounds__(256) void k_out(
    const unsigned short* __restrict__ hpad2, const unsigned short* __restrict__ htpad,
    const float* __restrict__ wsoft, const unsigned short* __restrict__ f2t,
    const float* __restrict__ Wout, const float* __restrict__ kconst,
    const float* __restrict__ labels, float* __restrict__ out)
{
  int p0 = blockIdx.x * K6P;
  int tid = threadIdx.x;
  __shared__ float s_w[K6P][NCH];
  __shared__ unsigned short s_f[K6P*K6K];   // swizzled, stride 1280B
  __shared__ float s_red[4][K6P];

  for (int i = tid; i < K6P*NCH; i += 256){
    int ps = i / NCH, c = i - ps*NCH;
    int p = p0 + ps;
    int b = p >> 6, t = p & 63;
    int idx = b*NCH + c;            // reference reshape scramble
    s_w[ps][c] = wsoft[((size_t)t*NCH + (idx>>7))*NB + (idx & 127)];
  }
  __syncthreads();

  // fusion[p][0:300]=sum_c h*w ; [300:600]=htarget ; [600:640]=0
  for (int it = tid; it < K6P*(K6K/8); it += 256){
    int ps = it / (K6K/8);
    int d0 = (it - ps*(K6K/8)) * 8;
    int p  = p0 + ps;
    unsigned short pk[8];
    if (d0 <= 288){                       // pure h part (d0+7 <= 295 < 300)
      float a8[8];
      #pragma unroll
      for (int k=0; k<8; k++) a8[k] = 0.f;
      #pragma unroll
      for (int c=0; c<NCH; c++){
        short8 v = *(const short8*)(hpad2 + (size_t)(c*8192 + p)*KPAD + d0);
        float wc = s_w[ps][c];
        #pragma unroll
        for (int k=0; k<8; k++) a8[k] += bf2f((unsigned short)v[k]) * wc;
      }
      #pragma unroll
      for (int k=0; k<8; k++) pk[k] = f2bf(a8[k]);
    } else if (d0 == 296){                // mixed boundary 296..303
      #pragma unroll
      for (int k=0; k<8; k++){
        int d = 296 + k;
        float v;
        if (d < 300){
          v = 0.f;
          #pragma unroll
          for (int c=0; c<NCH; c++)
            v += bf2f(hpad2[(size_t)(c*8192 + p)*KPAD + d]) * s_w[ps][c];
          pk[k] = f2bf(v);
        } else {
          pk[k] = htpad[(size_t)p*KPAD + (d - 300)];
        }
      }
    } else if (d0 < 600){                 // pure htarget (304..592)
      const unsigned short* hp = htpad + (size_t)p*KPAD + (d0 - 300);
      short4v v0 = *(const short4v*)hp;
      short4v v1 = *(const short4v*)(hp + 4);
      #pragma unroll
      for (int k=0; k<4; k++){ pk[k] = (unsigned short)v0[k]; pk[4+k] = (unsigned short)v1[k]; }
    } else {
      #pragma unroll
      for (int k=0; k<8; k++) pk[k] = 0;
    }
    short8 o;
    #pragma unroll
    for (int k=0; k<8; k++) o[k] = (short)pk[k];
    *(short8*)&s_f[swzi(ps, d0, K6K)] = o;
  }
  __syncthreads();

  // GEMM: [16 x 640] x [640 x 208], wave w owns nt = w, w+4, w+8, (w==0: 12)
  int wave = tid >> 6, lane = tid & 63;
  int lr = lane & 15, lg = lane >> 4;
  f32x4 acc[4];
  #pragma unroll
  for (int t4=0; t4<4; t4++) acc[t4] = (f32x4){0.f,0.f,0.f,0.f};
  for (int k0=0; k0<K6K; k0+=32){
    short8 a = *(const short8*)&s_f[swzi(lr, lg*8 + k0, K6K)];
    #pragma unroll
    for (int t4=0; t4<4; t4++){
      int nt = wave + t4*4;
      if (nt < NTI){
        short8 b = *(const short8*)(f2t + (size_t)(nt*16 + lr)*K6K + lg*8 + k0);
        acc[t4] = __builtin_amdgcn_mfma_f32_16x16x32_bf16(a, b, acc[t4], 0, 0, 0);
      }
    }
  }
  float part[4] = {0.f,0.f,0.f,0.f};
  #pragma unroll
  for (int t4=0; t4<4; t4++){
    int nt = wave + t4*4;
    if (nt < NTI){
      int e = nt*16 + lr;
      float wv = (e < 200) ? Wout[e] : 0.f;
      #pragma unroll
      for (int i=0; i<4; i++) part[i] += acc[t4][i] * wv;
    }
  }
  #pragma unroll
  for (int i=0; i<4; i++){
    float s = part[i];
    s += __shfl_xor(s, 1);
    s += __shfl_xor(s, 2);
    s += __shfl_xor(s, 4);
    s += __shfl_xor(s, 8);
    if (lr == 0) s_red[wave][lg*4 + i] = s;
  }
  __syncthreads();
  if (tid < K6P){
    float sum = s_red[0][tid] + s_red[1][tid] + s_red[2][tid] + s_red[3][tid] + kconst[0];
    int p = p0 + tid;
    int b = p >> 6, t = p & 63;
    out[(size_t)t*NB + b] = sum;
    out[NP + (size_t)t*NB + b] = labels[p];
  }
}

extern "C" void kernel_launch(void* const* d_in, const int* in_sizes, int n_in,
                              void* d_out, int out_size, void* d_ws, size_t ws_size,
                              hipStream_t stream)
{
  const float* li     = (const float*)d_in[0];
  const float* labels = (const float*)d_in[1];
  const float* extras = (const float*)d_in[2];
  const float* Wih    = (const float*)d_in[5];
  const float* bih    = (const float*)d_in[6];
  const float* bhh    = (const float*)d_in[7];
  const float* Wt     = (const float*)d_in[8];
  const float* bti    = (const float*)d_in[9];
  const float* bth    = (const float*)d_in[10];
  const float* Att1   = (const float*)d_in[11];
  const float* ba1    = (const float*)d_in[12];
  const float* Att2   = (const float*)d_in[13];
  const float* ba2    = (const float*)d_in[14];
  const float* fuse2  = (const float*)d_in[15];
  const float* bf2    = (const float*)d_in[16];
  const float* Wout   = (const float*)d_in[17];
  const float* bout   = (const float*)d_in[18];
  float* out = (float*)d_out;

  char* ws = (char*)d_ws;
  unsigned short* hpad2 = (unsigned short*)ws;                      // 62,914,560
  unsigned short* htpad = (unsigned short*)(ws + 62914560);         //  5,242,880
  float* ta     = (float*)(ws + 68157440);                          //  6,553,600
  float* score  = (float*)(ws + 74711040);                          //    393,216
  float* wsoft  = (float*)(ws + 75104256);                          //    393,216
  unsigned short* a1hi = (unsigned short*)(ws + 75497472);          //    133,120
  unsigned short* a1lo = (unsigned short*)(ws + 75630592);          //    133,120
  unsigned short* f2t  = (unsigned short*)(ws + 75763712);          //    266,240
  float* kconst = (float*)(ws + 76029952);                          //          4

  k_prep<<<1041, 256, 0, stream>>>(Att1, fuse2, bf2, Wout, bout,
                                   a1hi, a1lo, f2t, kconst);
  k_htarget<<<NP*KPAD/256, 256, 0, stream>>>(extras, Wt, bti, bth, htpad);
  k_ta<<<NP/64, 256, 0, stream>>>(htpad, a1lo, ta);
  k_hs<<<NCH*128, 256, 0, stream>>>(li, Wih, bih, bhh, a1hi, ta, ba1, Att2, ba2,
                                    hpad2, score);
  k_softmax<<<NTT, NB, 0, stream>>>(score, wsoft);
  k_out<<<NP/K6P, 256, 0, stream>>>(hpad2, htpad, wsoft, f2t, Wout, kconst,
                                    labels, out);
}

// Round 5
// 312.952 us; speedup vs baseline: 1.2789x; 1.0499x over previous
//
#include <hip/hip_runtime.h>
#include <hip/hip_bf16.h>

#define HH   300
#define NB   128
#define NTT  64
#define NP   8192        // B*T
#define NCH  12
#define KPAD 320         // padded K (300 -> 320)
#define NTI  13          // 208/16 n-tiles
#define K6K  640         // k_out padded K (600 -> 640)

typedef __attribute__((ext_vector_type(8))) short short8;
typedef __attribute__((ext_vector_type(4))) short short4v;
typedef __attribute__((ext_vector_type(4))) float f32x4;

__device__ __forceinline__ float fsig(float x){
  return __builtin_amdgcn_rcpf(1.f + __expf(-x));
}
__device__ __forceinline__ float ftanh(float x){
  float e = __expf(2.f*x);
  return 1.f - 2.f*__builtin_amdgcn_rcpf(e + 1.f);   // safe at +/-inf
}
__device__ __forceinline__ float bf2f(unsigned short u){
  return __uint_as_float(((unsigned)u) << 16);
}
__device__ __forceinline__ unsigned short f2bf(float f){
  __hip_bfloat16 h = __float2bfloat16(f);
  return *reinterpret_cast<unsigned short*>(&h);
}
// XOR-swizzled LDS short-index; strideShorts*2 must be a multiple of 128B
__device__ __forceinline__ int swzi(int row, int col, int strideShorts){
  int byte = row*(strideShorts*2) + (col<<1);
  byte ^= (row & 7) << 4;
  return byte >> 1;
}

// ---------- K0: weight tables (bf16, transposed, padded) + epilogue constant
// a1hi[208][320]=Att1[300+k][e]; a1lo[208][320]=Att1[k][e]; f2t[208][640]=fuse2[d][e]
// wg3[c][960][8]: i/g/o gate weights (j padded to 320 with 0); bsum3[c][960]: b_ih+b_hh
// kconst = sum_e bf2[e]*Wout[e] + bout
__global__ __launch_bounds__(256) void k_prep(
    const float* __restrict__ Att1, const float* __restrict__ fuse2,
    const float* __restrict__ bf2, const float* __restrict__ Wout,
    const float* __restrict__ bout, const float* __restrict__ Wih,
    const float* __restrict__ bih, const float* __restrict__ bhh,
    unsigned short* __restrict__ a1hi, unsigned short* __restrict__ a1lo,
    unsigned short* __restrict__ f2t, unsigned short* __restrict__ wg3,
    float* __restrict__ bsum3, float* __restrict__ kconst)
{
  int bid = blockIdx.x, tid = threadIdx.x;
  if (bid == 1445){
    __shared__ float red[256];
    red[tid] = (tid < 200) ? bf2[tid]*Wout[tid] : 0.f;
    __syncthreads();
    for (int s=128; s>0; s>>=1){
      if (tid < s) red[tid] += red[tid+s];
      __syncthreads();
    }
    if (tid == 0) kconst[0] = red[0] + bout[0];
    return;
  }
  int id = bid*256 + tid;
  if (id < 66560){
    int e = id/320, k = id - e*320;
    float v = (e<200 && k<300) ? Att1[(size_t)(300+k)*200 + e] : 0.f;
    a1hi[id] = f2bf(v);
  } else if (id < 133120){
    int j = id - 66560, e = j/320, k = j - e*320;
    float v = (e<200 && k<300) ? Att1[(size_t)k*200 + e] : 0.f;
    a1lo[j] = f2bf(v);
  } else if (id < 266240){
    int j = id - 133120, e = j/K6K, d = j - e*K6K;
    float v = (e<200 && d<600) ? fuse2[(size_t)d*200 + e] : 0.f;
    f2t[j] = f2bf(v);
  } else if (id < 358400){
    int idx = id - 266240;
    int c = idx / 7680, rem = idx - c*7680;
    int np = rem >> 3, f = rem & 7;
    int G = np / 320, j = np - G*320;
    int off = (G==0) ? 0 : (G==1) ? 600 : 900;
    float v = (j<300) ? Wih[(size_t)c*9600 + (size_t)(off+j)*8 + f] : 0.f;
    wg3[id - 266240] = f2bf(v);
  } else {
    int idx = id - 358400;   // < 11520
    int c = idx / 960, np = idx - c*960;
    int G = np / 320, j = np - G*320;
    int off = (G==0) ? 0 : (G==1) ? 600 : 900;
    bsum3[idx] = (j<300) ? (bih[c*1200+off+j] + bhh[c*1200+off+j]) : 0.f;
  }
}

// ---------- K1: htarget bf16 [8192][320] (zero-padded cols 300..319)
__global__ __launch_bounds__(256) void k_htarget(
    const float* __restrict__ extras, const float* __restrict__ Wt,
    const float* __restrict__ bti, const float* __restrict__ bth,
    unsigned short* __restrict__ htpad)
{
  int id = blockIdx.x*256 + threadIdx.x;   // NP*320
  int p = id / 320, j = id - p*320;
  if (j >= 300){ htpad[id] = 0; return; }
  const float* tg = extras + (size_t)p*17;
  float tv[5];
  #pragma unroll
  for (int f=0; f<5; f++) tv[f] = tg[f];
  float gi = bti[j]     + bth[j];
  float gg = bti[j+600] + bth[j+600];
  float go = bti[j+900] + bth[j+900];
  const float* w0 = Wt + (size_t)j*5;
  const float* w1 = Wt + (size_t)(j+600)*5;
  const float* w2 = Wt + (size_t)(j+900)*5;
  #pragma unroll
  for (int f=0; f<5; f++){ gi += tv[f]*w0[f]; gg += tv[f]*w1[f]; go += tv[f]*w2[f]; }
  float cc = fsig(gi)*ftanh(gg);
  htpad[id] = f2bf(fsig(go)*ftanh(cc));
}

// ---------- K2: ta[8192][200] = htarget . Att1[0:300,:]  via MFMA
__global__ __launch_bounds__(256) void k_ta(
    const unsigned short* __restrict__ htpad,
    const unsigned short* __restrict__ a1lo, float* __restrict__ ta)
{
  int wave = threadIdx.x >> 6, lane = threadIdx.x & 63;
  int lr = lane & 15, lg = lane >> 4;
  int r0 = blockIdx.x*64 + wave*16;
  f32x4 acc[NTI];
  #pragma unroll
  for (int nt=0; nt<NTI; nt++) acc[nt] = (f32x4){0.f,0.f,0.f,0.f};
  const unsigned short* ap = htpad + (size_t)(r0+lr)*KPAD + lg*8;
  const unsigned short* bp = a1lo + (size_t)lr*KPAD + lg*8;
  for (int k0=0; k0<KPAD; k0+=32){
    short8 a = *(const short8*)(ap + k0);
    #pragma unroll
    for (int nt=0; nt<NTI; nt++){
      short8 b = *(const short8*)(bp + (size_t)nt*16*KPAD + k0);
      acc[nt] = __builtin_amdgcn_mfma_f32_16x16x32_bf16(a, b, acc[nt], 0, 0, 0);
    }
  }
  #pragma unroll
  for (int nt=0; nt<NTI; nt++){
    int e = nt*16 + lr;
    if (e < 200){
      #pragma unroll
      for (int i=0; i<4; i++)
        ta[(size_t)(r0 + lg*4 + i)*200 + e] = acc[nt][i];
    }
  }
}

// ---------- K3: MFMA gate-GEMM + transcendental tail + score MFMA
// block: c = bid>>7, 64 consecutive p.  h stored hpad2[(c*8192+p)*320+j]
__global__ __launch_bounds__(256) void k_hs(
    const float* __restrict__ li, const unsigned short* __restrict__ wg3,
    const float* __restrict__ bsum3,
    const unsigned short* __restrict__ a1hi, const float* __restrict__ ta,
    const float* __restrict__ ba1, const float* __restrict__ att2,
    const float* __restrict__ ba2, unsigned short* __restrict__ hpad2,
    float* __restrict__ score)
{
  int c  = blockIdx.x >> 7;
  int p0 = (blockIdx.x & 127) << 6;
  int tid = threadIdx.x;
  int wave = tid >> 6, lane = tid & 63;
  int lr = lane & 15, lg = lane >> 4;
  __shared__ __align__(16) unsigned short s_sb[64*8];
  __shared__ __align__(16) unsigned short s_h[64*KPAD];  // swizzled, stride 640B

  for (int i = tid; i < 64*8; i += 256){
    int ps = i >> 3, f = i & 7;
    s_sb[i] = f2bf(li[(size_t)(p0+ps)*240 + f*12 + c]);
  }
  __syncthreads();

  // phase 1: gates via MFMA (K=8 in the lg==0 k-slot, rest zero) + elementwise
  short8 z8 = (short8){0,0,0,0,0,0,0,0};
  short8 afrag = z8;
  if (lg == 0) afrag = *(const short8*)&s_sb[(wave*16 + lr)*8];
  const unsigned short* wgc = wg3 + (size_t)c*960*8;
  const float* bsc = bsum3 + (size_t)c*960;
  f32x4 zero4 = (f32x4){0.f,0.f,0.f,0.f};
  int rowb = wave*16 + lg*4;
  for (int ch = 0; ch < 20; ch++){
    int n0 = ch*16;
    short8 bi8 = z8, bg8 = z8, bo8 = z8;
    if (lg == 0){
      bi8 = *(const short8*)&wgc[(size_t)(      n0 + lr)*8];
      bg8 = *(const short8*)&wgc[(size_t)(320 + n0 + lr)*8];
      bo8 = *(const short8*)&wgc[(size_t)(640 + n0 + lr)*8];
    }
    f32x4 gi4 = __builtin_amdgcn_mfma_f32_16x16x32_bf16(afrag, bi8, zero4, 0, 0, 0);
    f32x4 gg4 = __builtin_amdgcn_mfma_f32_16x16x32_bf16(afrag, bg8, zero4, 0, 0, 0);
    f32x4 go4 = __builtin_amdgcn_mfma_f32_16x16x32_bf16(afrag, bo8, zero4, 0, 0, 0);
    float bi = bsc[      n0 + lr];
    float bg = bsc[320 + n0 + lr];
    float bo = bsc[640 + n0 + lr];
    #pragma unroll
    for (int i2=0; i2<4; i2++){
      float gi = gi4[i2] + bi;
      float gg = gg4[i2] + bg;
      float go = go4[i2] + bo;
      float cc = fsig(gi)*ftanh(gg);
      float hv = fsig(go)*ftanh(cc);
      s_h[swzi(rowb + i2, n0 + lr, KPAD)] = f2bf(hv);
    }
  }
  __syncthreads();

  // dump s_h -> hpad2 (16B coalesced; swizzle XOR permutes 16B blocks only)
  unsigned short* gout = hpad2 + (size_t)(c*8192 + p0)*KPAD;
  for (int idx = tid; idx < 64*40; idx += 256){
    int row = idx / 40, c8 = idx - row*40;
    short8 v = *(const short8*)&s_h[swzi(row, c8*8, KPAD)];
    *(short8*)&gout[(size_t)row*KPAD + c8*8] = v;
  }

  // phase 2: per wave one 16-row m-tile x 13 n-tiles, K=320
  f32x4 acc[NTI];
  #pragma unroll
  for (int nt=0; nt<NTI; nt++) acc[nt] = zero4;
  const unsigned short* bp = a1hi + (size_t)lr*KPAD + lg*8;
  int arow = wave*16 + lr;
  for (int k0=0; k0<KPAD; k0+=32){
    short8 a = *(const short8*)&s_h[swzi(arow, lg*8 + k0, KPAD)];
    #pragma unroll
    for (int nt=0; nt<NTI; nt++){
      short8 b = *(const short8*)(bp + (size_t)nt*16*KPAD + k0);
      acc[nt] = __builtin_amdgcn_mfma_f32_16x16x32_bf16(a, b, acc[nt], 0, 0, 0);
    }
  }

  // epilogue: relu(acc + ta + ba1) . att2  -> score[p*12+c]
  float w200 = att2[200], w201 = att2[201], b2 = ba2[0];
  float sacc[4] = {0.f,0.f,0.f,0.f};
  #pragma unroll
  for (int nt=0; nt<NTI; nt++){
    int e = nt*16 + lr;
    if (e < 200){
      float b1  = ba1[e];
      float a2v = att2[e];
      #pragma unroll
      for (int i=0; i<4; i++){
        int p = p0 + wave*16 + lg*4 + i;
        float v = acc[nt][i] + ta[(size_t)p*200 + e] + b1;
        sacc[i] += fmaxf(v, 0.f) * a2v;
      }
    }
  }
  #pragma unroll
  for (int i=0; i<4; i++){
    float s = sacc[i];
    s += __shfl_xor(s, 1);
    s += __shfl_xor(s, 2);
    s += __shfl_xor(s, 4);
    s += __shfl_xor(s, 8);
    if (lr == 0){
      int p = p0 + wave*16 + lg*4 + i;
      float w0 = li[(size_t)p*240 + 84 + c];   // local_inputs[p,7,c]
      float w1 = li[(size_t)p*240 + 72 + c];   // local_inputs[p,6,c]
      score[(size_t)p*NCH + c] = fmaxf(s + w0*w200 + w1*w201 + b2, 0.f);
    }
  }
}

// ---------- K4: softmax over channels -> wsoft[t][c][b]
__global__ void k_softmax(const float* __restrict__ score, float* __restrict__ wsoft)
{
  int t = blockIdx.x;
  int b = threadIdx.x;
  const float* s = score + ((size_t)b*NTT + t)*NCH;
  float v[NCH];
  float m = -1e30f;
  #pragma unroll
  for (int c=0; c<NCH; c++){ v[c] = s[c]; m = fmaxf(m, v[c]); }
  float sum = 0.f;
  #pragma unroll
  for (int c=0; c<NCH; c++){ v[c] = __expf(v[c]-m); sum += v[c]; }
  float inv = __builtin_amdgcn_rcpf(sum);
  #pragma unroll
  for (int c=0; c<NCH; c++)
    wsoft[((size_t)t*NCH + c)*NB + b] = v[c]*inv;
}

// ---------- K5: fusion build (bf16 LDS) + MFMA vs fuse2^T + Wout dot
#define K6P 16
__global__ __launch_bounds__(256) void k_out(
    const unsigned short* __restrict__ hpad2, const unsigned short* __restrict__ htpad,
    const float* __restrict__ wsoft, const unsigned short* __restrict__ f2t,
    const float* __restrict__ Wout, const float* __restrict__ kconst,
    const float* __restrict__ labels, float* __restrict__ out)
{
  int p0 = blockIdx.x * K6P;
  int tid = threadIdx.x;
  __shared__ float s_w[K6P][NCH];
  __shared__ __align__(16) unsigned short s_f[K6P*K6K];   // swizzled, stride 1280B
  __shared__ float s_red[4][K6P];

  for (int i = tid; i < K6P*NCH; i += 256){
    int ps = i / NCH, c = i - ps*NCH;
    int p = p0 + ps;
    int b = p >> 6, t = p & 63;
    int idx = b*NCH + c;            // reference reshape scramble
    s_w[ps][c] = wsoft[((size_t)t*NCH + (idx>>7))*NB + (idx & 127)];
  }
  __syncthreads();

  // fusion[p][0:300]=sum_c h*w ; [300:600]=htarget ; [600:640]=0
  for (int it = tid; it < K6P*(K6K/8); it += 256){
    int ps = it / (K6K/8);
    int d0 = (it - ps*(K6K/8)) * 8;
    int p  = p0 + ps;
    unsigned short pk[8];
    if (d0 <= 288){                       // pure h part (d0+7 <= 295 < 300)
      float a8[8];
      #pragma unroll
      for (int k=0; k<8; k++) a8[k] = 0.f;
      #pragma unroll
      for (int c=0; c<NCH; c++){
        short8 v = *(const short8*)(hpad2 + (size_t)(c*8192 + p)*KPAD + d0);
        float wc = s_w[ps][c];
        #pragma unroll
        for (int k=0; k<8; k++) a8[k] += bf2f((unsigned short)v[k]) * wc;
      }
      #pragma unroll
      for (int k=0; k<8; k++) pk[k] = f2bf(a8[k]);
    } else if (d0 == 296){                // mixed boundary 296..303
      #pragma unroll
      for (int k=0; k<8; k++){
        int d = 296 + k;
        if (d < 300){
          float v = 0.f;
          #pragma unroll
          for (int c=0; c<NCH; c++)
            v += bf2f(hpad2[(size_t)(c*8192 + p)*KPAD + d]) * s_w[ps][c];
          pk[k] = f2bf(v);
        } else {
          pk[k] = htpad[(size_t)p*KPAD + (d - 300)];
        }
      }
    } else if (d0 < 600){                 // pure htarget (304..592)
      const unsigned short* hp = htpad + (size_t)p*KPAD + (d0 - 300);
      short4v v0 = *(const short4v*)hp;
      short4v v1 = *(const short4v*)(hp + 4);
      #pragma unroll
      for (int k=0; k<4; k++){ pk[k] = (unsigned short)v0[k]; pk[4+k] = (unsigned short)v1[k]; }
    } else {
      #pragma unroll
      for (int k=0; k<8; k++) pk[k] = 0;
    }
    short8 o;
    #pragma unroll
    for (int k=0; k<8; k++) o[k] = (short)pk[k];
    *(short8*)&s_f[swzi(ps, d0, K6K)] = o;
  }
  __syncthreads();

  // GEMM: [16 x 640] x [640 x 208], wave w owns nt = w, w+4, w+8, (w==0: 12)
  int wave = tid >> 6, lane = tid & 63;
  int lr = lane & 15, lg = lane >> 4;
  f32x4 acc[4];
  #pragma unroll
  for (int t4=0; t4<4; t4++) acc[t4] = (f32x4){0.f,0.f,0.f,0.f};
  for (int k0=0; k0<K6K; k0+=32){
    short8 a = *(const short8*)&s_f[swzi(lr, lg*8 + k0, K6K)];
    #pragma unroll
    for (int t4=0; t4<4; t4++){
      int nt = wave + t4*4;
      if (nt < NTI){
        short8 b = *(const short8*)(f2t + (size_t)(nt*16 + lr)*K6K + lg*8 + k0);
        acc[t4] = __builtin_amdgcn_mfma_f32_16x16x32_bf16(a, b, acc[t4], 0, 0, 0);
      }
    }
  }
  float part[4] = {0.f,0.f,0.f,0.f};
  #pragma unroll
  for (int t4=0; t4<4; t4++){
    int nt = wave + t4*4;
    if (nt < NTI){
      int e = nt*16 + lr;
      float wv = (e < 200) ? Wout[e] : 0.f;
      #pragma unroll
      for (int i=0; i<4; i++) part[i] += acc[t4][i] * wv;
    }
  }
  #pragma unroll
  for (int i=0; i<4; i++){
    float s = part[i];
    s += __shfl_xor(s, 1);
    s += __shfl_xor(s, 2);
    s += __shfl_xor(s, 4);
    s += __shfl_xor(s, 8);
    if (lr == 0) s_red[wave][lg*4 + i] = s;
  }
  __syncthreads();
  if (tid < K6P){
    float sum = s_red[0][tid] + s_red[1][tid] + s_red[2][tid] + s_red[3][tid] + kconst[0];
    int p = p0 + tid;
    int b = p >> 6, t = p & 63;
    out[(size_t)t*NB + b] = sum;
    out[NP + (size_t)t*NB + b] = labels[p];
  }
}

extern "C" void kernel_launch(void* const* d_in, const int* in_sizes, int n_in,
                              void* d_out, int out_size, void* d_ws, size_t ws_size,
                              hipStream_t stream)
{
  const float* li     = (const float*)d_in[0];
  const float* labels = (const float*)d_in[1];
  const float* extras = (const float*)d_in[2];
  const float* Wih    = (const float*)d_in[5];
  const float* bih    = (const float*)d_in[6];
  const float* bhh    = (const float*)d_in[7];
  const float* Wt     = (const float*)d_in[8];
  const float* bti    = (const float*)d_in[9];
  const float* bth    = (const float*)d_in[10];
  const float* Att1   = (const float*)d_in[11];
  const float* ba1    = (const float*)d_in[12];
  const float* Att2   = (const float*)d_in[13];
  const float* ba2    = (const float*)d_in[14];
  const float* fuse2  = (const float*)d_in[15];
  const float* bf2    = (const float*)d_in[16];
  const float* Wout   = (const float*)d_in[17];
  const float* bout   = (const float*)d_in[18];
  float* out = (float*)d_out;

  char* ws = (char*)d_ws;
  unsigned short* hpad2 = (unsigned short*)ws;                      // 62,914,560
  unsigned short* htpad = (unsigned short*)(ws + 62914560);         //  5,242,880
  float* ta     = (float*)(ws + 68157440);                          //  6,553,600
  float* score  = (float*)(ws + 74711040);                          //    393,216
  float* wsoft  = (float*)(ws + 75104256);                          //    393,216
  unsigned short* a1hi = (unsigned short*)(ws + 75497472);          //    133,120
  unsigned short* a1lo = (unsigned short*)(ws + 75630592);          //    133,120
  unsigned short* f2t  = (unsigned short*)(ws + 75763712);          //    266,240
  unsigned short* wg3  = (unsigned short*)(ws + 76029952);          //    184,320
  float* bsum3  = (float*)(ws + 76214272);                          //     46,080
  float* kconst = (float*)(ws + 76260352);                          //          4

  k_prep<<<1446, 256, 0, stream>>>(Att1, fuse2, bf2, Wout, bout, Wih, bih, bhh,
                                   a1hi, a1lo, f2t, wg3, bsum3, kconst);
  k_htarget<<<NP*KPAD/256, 256, 0, stream>>>(extras, Wt, bti, bth, htpad);
  k_ta<<<NP/64, 256, 0, stream>>>(htpad, a1lo, ta);
  k_hs<<<NCH*128, 256, 0, stream>>>(li, wg3, bsum3, a1hi, ta, ba1, Att2, ba2,
                                    hpad2, score);
  k_softmax<<<NTT, NB, 0, stream>>>(score, wsoft);
  k_out<<<NP/K6P, 256, 0, stream>>>(hpad2, htpad, wsoft, f2t, Wout, kconst,
                                    labels, out);
}

// Round 6
// 241.191 us; speedup vs baseline: 1.6594x; 1.2975x over previous
//
#include <hip/hip_runtime.h>
#include <hip/hip_bf16.h>

#define HH   300
#define NB   128
#define NTT  64
#define NP   8192        // B*T
#define NCH  12
#define KPAD 320         // padded K (300 -> 320)
#define NTI  13          // 208/16 n-tiles
#define K6K  640         // k_out padded K (600 -> 640)

typedef __attribute__((ext_vector_type(8))) short short8;
typedef __attribute__((ext_vector_type(4))) short short4v;
typedef __attribute__((ext_vector_type(4))) float f32x4;

__device__ __forceinline__ float fsig(float x){
  return __builtin_amdgcn_rcpf(1.f + __expf(-x));
}
__device__ __forceinline__ float ftanh(float x){
  float e = __expf(2.f*x);
  return 1.f - 2.f*__builtin_amdgcn_rcpf(e + 1.f);   // safe at +/-inf
}
__device__ __forceinline__ float bf2f(unsigned short u){
  return __uint_as_float(((unsigned)u) << 16);
}
__device__ __forceinline__ unsigned short f2bf(float f){
  __hip_bfloat16 h = __float2bfloat16(f);
  return *reinterpret_cast<unsigned short*>(&h);
}
// XOR-swizzled LDS short-index; strideShorts*2 must be a multiple of 128B
__device__ __forceinline__ int swzi(int row, int col, int strideShorts){
  int byte = row*(strideShorts*2) + (col<<1);
  byte ^= (row & 7) << 4;
  return byte >> 1;
}

// ---------- K0: weight tables (bf16, transposed, padded) + epilogue constant
__global__ __launch_bounds__(256) void k_prep(
    const float* __restrict__ Att1, const float* __restrict__ fuse2,
    const float* __restrict__ bf2, const float* __restrict__ Wout,
    const float* __restrict__ bout, const float* __restrict__ Wih,
    const float* __restrict__ bih, const float* __restrict__ bhh,
    unsigned short* __restrict__ a1hi, unsigned short* __restrict__ a1lo,
    unsigned short* __restrict__ f2t, unsigned short* __restrict__ wg3,
    float* __restrict__ bsum3, float* __restrict__ kconst)
{
  int bid = blockIdx.x, tid = threadIdx.x;
  if (bid == 1445){
    __shared__ float red[256];
    red[tid] = (tid < 200) ? bf2[tid]*Wout[tid] : 0.f;
    __syncthreads();
    for (int s=128; s>0; s>>=1){
      if (tid < s) red[tid] += red[tid+s];
      __syncthreads();
    }
    if (tid == 0) kconst[0] = red[0] + bout[0];
    return;
  }
  int id = bid*256 + tid;
  if (id < 66560){
    int e = id/320, k = id - e*320;
    float v = (e<200 && k<300) ? Att1[(size_t)(300+k)*200 + e] : 0.f;
    a1hi[id] = f2bf(v);
  } else if (id < 133120){
    int j = id - 66560, e = j/320, k = j - e*320;
    float v = (e<200 && k<300) ? Att1[(size_t)k*200 + e] : 0.f;
    a1lo[j] = f2bf(v);
  } else if (id < 266240){
    int j = id - 133120, e = j/K6K, d = j - e*K6K;
    float v = (e<200 && d<600) ? fuse2[(size_t)d*200 + e] : 0.f;
    f2t[j] = f2bf(v);
  } else if (id < 358400){
    int idx = id - 266240;
    int c = idx / 7680, rem = idx - c*7680;
    int np = rem >> 3, f = rem & 7;
    int G = np / 320, j = np - G*320;
    int off = (G==0) ? 0 : (G==1) ? 600 : 900;
    float v = (j<300) ? Wih[(size_t)c*9600 + (size_t)(off+j)*8 + f] : 0.f;
    wg3[id - 266240] = f2bf(v);
  } else {
    int idx = id - 358400;   // < 11520
    int c = idx / 960, np = idx - c*960;
    int G = np / 320, j = np - G*320;
    int off = (G==0) ? 0 : (G==1) ? 600 : 900;
    bsum3[idx] = (j<300) ? (bih[c*1200+off+j] + bhh[c*1200+off+j]) : 0.f;
  }
}

// ---------- K0b: Sbf[c][p][8] = bf16(li[p*240 + f*12 + c]) — coalesced repack
__global__ __launch_bounds__(256) void k_sprep(
    const float* __restrict__ li, unsigned short* __restrict__ Sbf)
{
  int pb0 = blockIdx.x * 8;
  int tid = threadIdx.x;
  __shared__ float s_li[8*240];
  for (int i = tid; i < 8*240; i += 256)
    s_li[i] = li[(size_t)pb0*240 + i];
  __syncthreads();
  for (int i = tid; i < 8*96; i += 256){
    int pp = i / 96, rem = i - pp*96;
    int c = rem >> 3, f = rem & 7;
    Sbf[((size_t)c*NP + pb0 + pp)*8 + f] = f2bf(s_li[pp*240 + f*12 + c]);
  }
}

// ---------- K1: htarget bf16 [8192][320] (zero-padded cols 300..319)
__global__ __launch_bounds__(256) void k_htarget(
    const float* __restrict__ extras, const float* __restrict__ Wt,
    const float* __restrict__ bti, const float* __restrict__ bth,
    unsigned short* __restrict__ htpad)
{
  int id = blockIdx.x*256 + threadIdx.x;   // NP*320
  int p = id / 320, j = id - p*320;
  if (j >= 300){ htpad[id] = 0; return; }
  const float* tg = extras + (size_t)p*17;
  float tv[5];
  #pragma unroll
  for (int f=0; f<5; f++) tv[f] = tg[f];
  float gi = bti[j]     + bth[j];
  float gg = bti[j+600] + bth[j+600];
  float go = bti[j+900] + bth[j+900];
  const float* w0 = Wt + (size_t)j*5;
  const float* w1 = Wt + (size_t)(j+600)*5;
  const float* w2 = Wt + (size_t)(j+900)*5;
  #pragma unroll
  for (int f=0; f<5; f++){ gi += tv[f]*w0[f]; gg += tv[f]*w1[f]; go += tv[f]*w2[f]; }
  float cc = fsig(gi)*ftanh(gg);
  htpad[id] = f2bf(fsig(go)*ftanh(cc));
}

// ---------- K2: ta[8192][200] = htarget . Att1[0:300,:]  via MFMA, 1 wave/block
__global__ __launch_bounds__(64) void k_ta(
    const unsigned short* __restrict__ htpad,
    const unsigned short* __restrict__ a1lo, float* __restrict__ ta)
{
  int lane = threadIdx.x;
  int lr = lane & 15, lg = lane >> 4;
  int r0 = blockIdx.x*16;
  f32x4 acc[NTI];
  #pragma unroll
  for (int nt=0; nt<NTI; nt++) acc[nt] = (f32x4){0.f,0.f,0.f,0.f};
  const unsigned short* ap = htpad + (size_t)(r0+lr)*KPAD + lg*8;
  const unsigned short* bp = a1lo + (size_t)lr*KPAD + lg*8;
  for (int k0=0; k0<KPAD; k0+=32){
    short8 a = *(const short8*)(ap + k0);
    #pragma unroll
    for (int nt=0; nt<NTI; nt++){
      short8 b = *(const short8*)(bp + (size_t)nt*16*KPAD + k0);
      acc[nt] = __builtin_amdgcn_mfma_f32_16x16x32_bf16(a, b, acc[nt], 0, 0, 0);
    }
  }
  #pragma unroll
  for (int nt=0; nt<NTI; nt++){
    int e = nt*16 + lr;
    if (e < 200){
      #pragma unroll
      for (int i=0; i<4; i++)
        ta[(size_t)(r0 + lg*4 + i)*200 + e] = acc[nt][i];
    }
  }
}

// ---------- K3: MFMA gate-GEMM + transcendental tail + n-split score MFMA
// block: c = bid>>7, 64 consecutive p.  h stored hpad2[(c*8192+p)*320+j]
__global__ __launch_bounds__(256, 4) void k_hs(
    const float* __restrict__ li, const unsigned short* __restrict__ Sbf,
    const unsigned short* __restrict__ wg3, const float* __restrict__ bsum3,
    const unsigned short* __restrict__ a1hi, const float* __restrict__ ta,
    const float* __restrict__ ba1, const float* __restrict__ att2,
    const float* __restrict__ ba2, unsigned short* __restrict__ hpad2,
    float* __restrict__ score)
{
  int c  = blockIdx.x >> 7;
  int p0 = (blockIdx.x & 127) << 6;
  int tid = threadIdx.x;
  int wave = tid >> 6, lane = tid & 63;
  int lr = lane & 15, lg = lane >> 4;
  __shared__ __align__(16) unsigned short s_h[64*KPAD];  // 40960 B exactly

  short8 z8 = (short8){0,0,0,0,0,0,0,0};
  // A-frag: S row (K=8 in lg==0 slot), loaded coalesced from Sbf
  short8 afrag = z8;
  if (lg == 0)
    afrag = *(const short8*)(Sbf + ((size_t)c*NP + p0 + wave*16 + lr)*8);

  // phase 1: gates via MFMA + elementwise tail, ch-pipelined B-frag loads
  const unsigned short* wgc = wg3 + (size_t)c*960*8;
  const float* bsc = bsum3 + (size_t)c*960;
  f32x4 zero4 = (f32x4){0.f,0.f,0.f,0.f};
  int rowb = wave*16 + lg*4;
  short8 nb0 = z8, nb1 = z8, nb2 = z8;
  if (lg == 0){
    nb0 = *(const short8*)&wgc[(size_t)(      lr)*8];
    nb1 = *(const short8*)&wgc[(size_t)(320 + lr)*8];
    nb2 = *(const short8*)&wgc[(size_t)(640 + lr)*8];
  }
  for (int ch = 0; ch < 20; ch++){
    int n0 = ch*16;
    short8 cb0 = nb0, cb1 = nb1, cb2 = nb2;
    if (ch < 19 && lg == 0){
      int nn = n0 + 16 + lr;
      nb0 = *(const short8*)&wgc[(size_t)(      nn)*8];
      nb1 = *(const short8*)&wgc[(size_t)(320 + nn)*8];
      nb2 = *(const short8*)&wgc[(size_t)(640 + nn)*8];
    }
    f32x4 gi4 = __builtin_amdgcn_mfma_f32_16x16x32_bf16(afrag, cb0, zero4, 0, 0, 0);
    f32x4 gg4 = __builtin_amdgcn_mfma_f32_16x16x32_bf16(afrag, cb1, zero4, 0, 0, 0);
    f32x4 go4 = __builtin_amdgcn_mfma_f32_16x16x32_bf16(afrag, cb2, zero4, 0, 0, 0);
    float bi = bsc[      n0 + lr];
    float bg = bsc[320 + n0 + lr];
    float bo = bsc[640 + n0 + lr];
    #pragma unroll
    for (int i2=0; i2<4; i2++){
      float gi = gi4[i2] + bi;
      float gg = gg4[i2] + bg;
      float go = go4[i2] + bo;
      float cc = fsig(gi)*ftanh(gg);
      float hv = fsig(go)*ftanh(cc);
      s_h[swzi(rowb + i2, n0 + lr, KPAD)] = f2bf(hv);
    }
  }
  __syncthreads();

  // dump s_h -> hpad2 (16B coalesced; swizzle XOR permutes 16B blocks only)
  unsigned short* gout = hpad2 + (size_t)(c*8192 + p0)*KPAD;
  for (int idx = tid; idx < 64*40; idx += 256){
    int row = idx / 40, c8 = idx - row*40;
    short8 v = *(const short8*)&s_h[swzi(row, c8*8, KPAD)];
    *(short8*)&gout[(size_t)row*KPAD + c8*8] = v;
  }

  // phase 2: n-split — wave w owns nt = w + 4*t4 (w0: 0,4,8,12), all 4 m-tiles
  f32x4 acc[4][4];
  #pragma unroll
  for (int mt=0; mt<4; mt++)
    #pragma unroll
    for (int t4=0; t4<4; t4++) acc[mt][t4] = zero4;
  for (int k0=0; k0<KPAD; k0+=32){
    short8 a[4];
    #pragma unroll
    for (int mt=0; mt<4; mt++)
      a[mt] = *(const short8*)&s_h[swzi(mt*16 + lr, lg*8 + k0, KPAD)];
    #pragma unroll
    for (int t4=0; t4<4; t4++){
      int nt = wave + t4*4;
      if (nt < NTI){
        short8 b = *(const short8*)(a1hi + (size_t)(nt*16 + lr)*KPAD + lg*8 + k0);
        #pragma unroll
        for (int mt=0; mt<4; mt++)
          acc[mt][t4] = __builtin_amdgcn_mfma_f32_16x16x32_bf16(a[mt], b, acc[mt][t4], 0, 0, 0);
      }
    }
  }

  // epilogue partials: relu(acc + ta + ba1) . att2 over this wave's nt-set
  float sacc[4][4];
  #pragma unroll
  for (int mt=0; mt<4; mt++)
    #pragma unroll
    for (int i=0; i<4; i++) sacc[mt][i] = 0.f;
  #pragma unroll
  for (int t4=0; t4<4; t4++){
    int nt = wave + t4*4;
    if (nt < NTI){
      int e = nt*16 + lr;
      if (e < 200){
        float b1  = ba1[e];
        float a2v = att2[e];
        #pragma unroll
        for (int mt=0; mt<4; mt++){
          #pragma unroll
          for (int i=0; i<4; i++){
            int p = p0 + mt*16 + lg*4 + i;
            float v = acc[mt][t4][i] + ta[(size_t)p*200 + e] + b1;
            sacc[mt][i] += fmaxf(v, 0.f) * a2v;
          }
        }
      }
    }
  }
  __syncthreads();                       // all s_h ds_reads done; safe to alias
  float* s_red = reinterpret_cast<float*>(s_h);   // [4][64]
  #pragma unroll
  for (int mt=0; mt<4; mt++){
    #pragma unroll
    for (int i=0; i<4; i++){
      float s = sacc[mt][i];
      s += __shfl_xor(s, 1);
      s += __shfl_xor(s, 2);
      s += __shfl_xor(s, 4);
      s += __shfl_xor(s, 8);
      if (lr == 0) s_red[wave*64 + mt*16 + lg*4 + i] = s;
    }
  }
  __syncthreads();
  if (tid < 64){
    float r = s_red[tid] + s_red[64+tid] + s_red[128+tid] + s_red[192+tid];
    int p = p0 + tid;
    float w200 = att2[200], w201 = att2[201], b2 = ba2[0];
    float w0 = li[(size_t)p*240 + 84 + c];   // local_inputs[p,7,c]
    float w1 = li[(size_t)p*240 + 72 + c];   // local_inputs[p,6,c]
    score[(size_t)p*NCH + c] = fmaxf(r + w0*w200 + w1*w201 + b2, 0.f);
  }
}

// ---------- K4: softmax over channels -> wsoft[t][c][b]
__global__ void k_softmax(const float* __restrict__ score, float* __restrict__ wsoft)
{
  int t = blockIdx.x;
  int b = threadIdx.x;
  const float* s = score + ((size_t)b*NTT + t)*NCH;
  float v[NCH];
  float m = -1e30f;
  #pragma unroll
  for (int c=0; c<NCH; c++){ v[c] = s[c]; m = fmaxf(m, v[c]); }
  float sum = 0.f;
  #pragma unroll
  for (int c=0; c<NCH; c++){ v[c] = __expf(v[c]-m); sum += v[c]; }
  float inv = __builtin_amdgcn_rcpf(sum);
  #pragma unroll
  for (int c=0; c<NCH; c++)
    wsoft[((size_t)t*NCH + c)*NB + b] = v[c]*inv;
}

// ---------- K5: fusion build (bf16 LDS) + MFMA vs fuse2^T + Wout dot
#define K6P 16
__global__ __launch_bounds__(256) void k_out(
    const unsigned short* __restrict__ hpad2, const unsigned short* __restrict__ htpad,
    const float* __restrict__ wsoft, const unsigned short* __restrict__ f2t,
    const float* __restrict__ Wout, const float* __restrict__ kconst,
    const float* __restrict__ labels, float* __restrict__ out)
{
  int p0 = blockIdx.x * K6P;
  int tid = threadIdx.x;
  __shared__ float s_w[K6P][NCH];
  __shared__ __align__(16) unsigned short s_f[K6P*K6K];   // swizzled, stride 1280B
  __shared__ float s_red[4][K6P];

  for (int i = tid; i < K6P*NCH; i += 256){
    int ps = i / NCH, c = i - ps*NCH;
    int p = p0 + ps;
    int b = p >> 6, t = p & 63;
    int idx = b*NCH + c;            // reference reshape scramble
    s_w[ps][c] = wsoft[((size_t)t*NCH + (idx>>7))*NB + (idx & 127)];
  }
  __syncthreads();

  // fusion[p][0:300]=sum_c h*w ; [300:600]=htarget ; [600:640]=0
  for (int it = tid; it < K6P*(K6K/8); it += 256){
    int ps = it / (K6K/8);
    int d0 = (it - ps*(K6K/8)) * 8;
    int p  = p0 + ps;
    unsigned short pk[8];
    if (d0 <= 288){                       // pure h part (d0+7 <= 295 < 300)
      float a8[8];
      #pragma unroll
      for (int k=0; k<8; k++) a8[k] = 0.f;
      #pragma unroll
      for (int c=0; c<NCH; c++){
        short8 v = *(const short8*)(hpad2 + (size_t)(c*8192 + p)*KPAD + d0);
        float wc = s_w[ps][c];
        #pragma unroll
        for (int k=0; k<8; k++) a8[k] += bf2f((unsigned short)v[k]) * wc;
      }
      #pragma unroll
      for (int k=0; k<8; k++) pk[k] = f2bf(a8[k]);
    } else if (d0 == 296){                // mixed boundary 296..303
      #pragma unroll
      for (int k=0; k<8; k++){
        int d = 296 + k;
        if (d < 300){
          float v = 0.f;
          #pragma unroll
          for (int c=0; c<NCH; c++)
            v += bf2f(hpad2[(size_t)(c*8192 + p)*KPAD + d]) * s_w[ps][c];
          pk[k] = f2bf(v);
        } else {
          pk[k] = htpad[(size_t)p*KPAD + (d - 300)];
        }
      }
    } else if (d0 < 600){                 // pure htarget (304..592)
      const unsigned short* hp = htpad + (size_t)p*KPAD + (d0 - 300);
      short4v v0 = *(const short4v*)hp;
      short4v v1 = *(const short4v*)(hp + 4);
      #pragma unroll
      for (int k=0; k<4; k++){ pk[k] = (unsigned short)v0[k]; pk[4+k] = (unsigned short)v1[k]; }
    } else {
      #pragma unroll
      for (int k=0; k<8; k++) pk[k] = 0;
    }
    short8 o;
    #pragma unroll
    for (int k=0; k<8; k++) o[k] = (short)pk[k];
    *(short8*)&s_f[swzi(ps, d0, K6K)] = o;
  }
  __syncthreads();

  // GEMM: [16 x 640] x [640 x 208], wave w owns nt = w, w+4, w+8, (w==0: 12)
  int wave = tid >> 6, lane = tid & 63;
  int lr = lane & 15, lg = lane >> 4;
  f32x4 acc[4];
  #pragma unroll
  for (int t4=0; t4<4; t4++) acc[t4] = (f32x4){0.f,0.f,0.f,0.f};
  for (int k0=0; k0<K6K; k0+=32){
    short8 a = *(const short8*)&s_f[swzi(lr, lg*8 + k0, K6K)];
    #pragma unroll
    for (int t4=0; t4<4; t4++){
      int nt = wave + t4*4;
      if (nt < NTI){
        short8 b = *(const short8*)(f2t + (size_t)(nt*16 + lr)*K6K + lg*8 + k0);
        acc[t4] = __builtin_amdgcn_mfma_f32_16x16x32_bf16(a, b, acc[t4], 0, 0, 0);
      }
    }
  }
  float part[4] = {0.f,0.f,0.f,0.f};
  #pragma unroll
  for (int t4=0; t4<4; t4++){
    int nt = wave + t4*4;
    if (nt < NTI){
      int e = nt*16 + lr;
      float wv = (e < 200) ? Wout[e] : 0.f;
      #pragma unroll
      for (int i=0; i<4; i++) part[i] += acc[t4][i] * wv;
    }
  }
  #pragma unroll
  for (int i=0; i<4; i++){
    float s = part[i];
    s += __shfl_xor(s, 1);
    s += __shfl_xor(s, 2);
    s += __shfl_xor(s, 4);
    s += __shfl_xor(s, 8);
    if (lr == 0) s_red[wave][lg*4 + i] = s;
  }
  __syncthreads();
  if (tid < K6P){
    float sum = s_red[0][tid] + s_red[1][tid] + s_red[2][tid] + s_red[3][tid] + kconst[0];
    int p = p0 + tid;
    int b = p >> 6, t = p & 63;
    out[(size_t)t*NB + b] = sum;
    out[NP + (size_t)t*NB + b] = labels[p];
  }
}

extern "C" void kernel_launch(void* const* d_in, const int* in_sizes, int n_in,
                              void* d_out, int out_size, void* d_ws, size_t ws_size,
                              hipStream_t stream)
{
  const float* li     = (const float*)d_in[0];
  const float* labels = (const float*)d_in[1];
  const float* extras = (const float*)d_in[2];
  const float* Wih    = (const float*)d_in[5];
  const float* bih    = (const float*)d_in[6];
  const float* bhh    = (const float*)d_in[7];
  const float* Wt     = (const float*)d_in[8];
  const float* bti    = (const float*)d_in[9];
  const float* bth    = (const float*)d_in[10];
  const float* Att1   = (const float*)d_in[11];
  const float* ba1    = (const float*)d_in[12];
  const float* Att2   = (const float*)d_in[13];
  const float* ba2    = (const float*)d_in[14];
  const float* fuse2  = (const float*)d_in[15];
  const float* bf2    = (const float*)d_in[16];
  const float* Wout   = (const float*)d_in[17];
  const float* bout   = (const float*)d_in[18];
  float* out = (float*)d_out;

  char* ws = (char*)d_ws;
  unsigned short* hpad2 = (unsigned short*)ws;                      // 62,914,560
  unsigned short* htpad = (unsigned short*)(ws + 62914560);         //  5,242,880
  float* ta     = (float*)(ws + 68157440);                          //  6,553,600
  float* score  = (float*)(ws + 74711040);                          //    393,216
  float* wsoft  = (float*)(ws + 75104256);                          //    393,216
  unsigned short* a1hi = (unsigned short*)(ws + 75497472);          //    133,120
  unsigned short* a1lo = (unsigned short*)(ws + 75630592);          //    133,120
  unsigned short* f2t  = (unsigned short*)(ws + 75763712);          //    266,240
  unsigned short* wg3  = (unsigned short*)(ws + 76029952);          //    184,320
  float* bsum3  = (float*)(ws + 76214272);                          //     46,080
  unsigned short* Sbf  = (unsigned short*)(ws + 76260352);          //  1,572,864
  float* kconst = (float*)(ws + 77833216);                          //          4

  k_prep<<<1446, 256, 0, stream>>>(Att1, fuse2, bf2, Wout, bout, Wih, bih, bhh,
                                   a1hi, a1lo, f2t, wg3, bsum3, kconst);
  k_sprep<<<NP/8, 256, 0, stream>>>(li, Sbf);
  k_htarget<<<NP*KPAD/256, 256, 0, stream>>>(extras, Wt, bti, bth, htpad);
  k_ta<<<NP/16, 64, 0, stream>>>(htpad, a1lo, ta);
  k_hs<<<NCH*128, 256, 0, stream>>>(li, Sbf, wg3, bsum3, a1hi, ta, ba1, Att2,
                                    ba2, hpad2, score);
  k_softmax<<<NTT, NB, 0, stream>>>(score, wsoft);
  k_out<<<NP/K6P, 256, 0, stream>>>(hpad2, htpad, wsoft, f2t, Wout, kconst,
                                    labels, out);
}